// Round 1
// baseline (308.562 us; speedup 1.0000x reference)
//
#include <hip/hip_runtime.h>
#include <hip/hip_bf16.h>

typedef __attribute__((ext_vector_type(8))) short bf16x8;
typedef __attribute__((ext_vector_type(4))) float f32x4;
typedef __attribute__((ext_vector_type(4))) int   i32x4;
typedef __attribute__((ext_vector_type(4))) unsigned short u16x4;
typedef unsigned short u16;

#define G_ 20000
#define B_ 512

__device__ __forceinline__ u16 f2bf(float x) {
  __hip_bfloat16 h = __float2bfloat16(x);   // RTN
  return __builtin_bit_cast(u16, h);
}
__device__ __forceinline__ float bf2f(u16 u) {
  unsigned int v = ((unsigned int)u) << 16;
  return __builtin_bit_cast(float, v);
}

// ---------------------------------------------------------------------------
// K1: per-gene micro-MLP  -> X tiled bf16  [k_tile][512][32], cols 0..19999
// ---------------------------------------------------------------------------
__global__ void k_gene(const float* __restrict__ expr,
                       const float* __restrict__ bw1, const float* __restrict__ bb1,
                       const float* __restrict__ bw2, const float* __restrict__ bb2,
                       const float* __restrict__ gw,  const float* __restrict__ gb,
                       u16* __restrict__ Xt) {
  int g = blockIdx.x * 256 + threadIdx.x;
  if (g >= G_) return;
  int b0 = blockIdx.y * 32;

  f32x4 w1a = ((const f32x4*)bw1)[g];
  f32x4 w1b = ((const f32x4*)bw1)[G_ + g];
  f32x4 b1a = ((const f32x4*)bb1)[g];
  f32x4 b1b = ((const f32x4*)bb1)[G_ + g];
  f32x4 w2a = ((const f32x4*)bw2)[g];
  f32x4 w2b = ((const f32x4*)bw2)[G_ + g];
  float bb2a = bb2[g], bb2b = bb2[G_ + g];
  float gw0 = gw[g * 2], gw1 = gw[g * 2 + 1];
  float gbg = gb[g];

  u16* outp = Xt + (size_t)(g >> 5) * 16384 + (g & 31);

  #pragma unroll 4
  for (int b = b0; b < b0 + 32; ++b) {
    float x0 = expr[(size_t)(b * 2) * G_ + g];
    float x1 = expr[(size_t)(b * 2 + 1) * G_ + g];
    float h0 = fmaxf(x0 * w1a.x + b1a.x, 0.f);
    float h1 = fmaxf(x0 * w1a.y + b1a.y, 0.f);
    float h2 = fmaxf(x0 * w1a.z + b1a.z, 0.f);
    float h3 = fmaxf(x0 * w1a.w + b1a.w, 0.f);
    float s0 = fmaxf(h0 * w2a.x + h1 * w2a.y + h2 * w2a.z + h3 * w2a.w + bb2a, 0.f);
    float g0 = fmaxf(x1 * w1b.x + b1b.x, 0.f);
    float g1 = fmaxf(x1 * w1b.y + b1b.y, 0.f);
    float g2 = fmaxf(x1 * w1b.z + b1b.z, 0.f);
    float g3 = fmaxf(x1 * w1b.w + b1b.w, 0.f);
    float s1 = fmaxf(g0 * w2b.x + g1 * w2b.y + g2 * w2b.z + g3 * w2b.w + bb2b, 0.f);
    float e = fmaxf(s0 * gw0 + s1 * gw1 + gbg, 0.f);
    outp[(size_t)b * 32] = f2bf(e);
  }
}

// ---------------------------------------------------------------------------
// K2: clinical features -> X tiles 625,626 (cols 20000..20063, zero-padded)
// ---------------------------------------------------------------------------
__global__ void k_clin(const int* __restrict__ cc, const float* __restrict__ cnc,
                       const float* __restrict__ race, const float* __restrict__ eth,
                       const float* __restrict__ inter, const float* __restrict__ prot,
                       const float* __restrict__ mw, const float* __restrict__ mb,
                       u16* __restrict__ Xt) {
  int b = threadIdx.x;  // 512 threads, 1 block
  int c0 = cc[b * 3], c1 = cc[b * 3 + 1], c2 = cc[b * 3 + 2];
  float nc[10];
  #pragma unroll
  for (int v = 0; v < 10; ++v)
    nc[v] = fmaxf(cnc[b * 20 + v] * mw[v * 2] + cnc[b * 20 + 10 + v] * mw[v * 2 + 1] + mb[v], 0.f);

  u16* t0 = Xt + (size_t)625 * 16384 + b * 32;
  u16* t1 = Xt + (size_t)626 * 16384 + b * 32;
  #pragma unroll
  for (int c = 0; c < 32; ++c) {
    float v;
    if (c < 8)       v = race[c0 * 8 + c];
    else if (c < 12) v = eth[c1 * 4 + (c - 8)];
    else if (c < 20) v = inter[(c0 * 4 + c1) * 8 + (c - 12)];
    else if (c < 28) v = prot[c2 * 8 + (c - 20)];
    else             v = nc[c - 28];
    t0[c] = f2bf(v);
  }
  #pragma unroll
  for (int c = 0; c < 32; ++c) {
    int j = 32 + c;
    float v = (j < 38) ? nc[j - 28] : 0.f;
    t1[c] = f2bf(v);
  }
}

// ---------------------------------------------------------------------------
// GEMM: part[split] += Xtile(512 x 32k bf16) @ W(fp32, converted)  BM=512 BN=128
// Xt: [nSteps][512][32] bf16.  W: [Kvalid][Nvalid] fp32 row-major.
// part: [S][512][Npad] fp32.
// ---------------------------------------------------------------------------
__global__ __launch_bounds__(512) void k_gemm(
    const u16* __restrict__ Xt, const float* __restrict__ W,
    float* __restrict__ part, int nSteps, int Kvalid, int Nvalid, int Npad) {
  __shared__ __align__(16) u16 Xs[512 * 40];  // rows padded to 40 elems (80 B)
  __shared__ __align__(16) u16 Ws[128 * 40];  // W^T tile [n][k]

  const int tid = threadIdx.x;
  const int nt = blockIdx.x, split = blockIdx.y, S = gridDim.y;
  const int n0 = nt * 128;
  const int ks0 = (int)(((long)split * nSteps) / S);
  const int ks1 = (int)(((long)(split + 1) * nSteps) / S);

  const int lane = tid & 63, wave = tid >> 6;
  const int wr = wave >> 1, wc = wave & 1;   // 4 x 2 wave grid, wave tile 128x64
  const int l15 = lane & 15, l4 = lane >> 4;
  const int xn = tid & 127, kq = tid >> 7;

  f32x4 acc[8][4];
  #pragma unroll
  for (int i = 0; i < 8; ++i)
    #pragma unroll
    for (int j = 0; j < 4; ++j)
      #pragma unroll
      for (int r = 0; r < 4; ++r) acc[i][j][r] = 0.f;

  i32x4 xreg[4];
  float wreg[8];
  const int nW = n0 + xn;
  const bool nok = nW < Nvalid;

  auto LOAD = [&](int ks) {
    const i32x4* src = (const i32x4*)(Xt + (size_t)ks * 16384);
    #pragma unroll
    for (int p = 0; p < 4; ++p) xreg[p] = src[p * 512 + tid];
    long kb = (long)ks * 32 + kq * 8;
    #pragma unroll
    for (int i = 0; i < 8; ++i) {
      long k = kb + i;
      wreg[i] = (nok && k < (long)Kvalid) ? W[k * (size_t)Nvalid + nW] : 0.f;
    }
  };
  auto STORE = [&]() {
    #pragma unroll
    for (int p = 0; p < 4; ++p) {
      int chunk = p * 512 + tid;
      int row = chunk >> 2, c = chunk & 3;
      *(i32x4*)&Xs[row * 40 + c * 8] = xreg[p];
    }
    u16 h[8];
    #pragma unroll
    for (int i = 0; i < 8; ++i) h[i] = f2bf(wreg[i]);
    i32x4 pk;
    pk[0] = (int)h[0] | ((int)h[1] << 16);
    pk[1] = (int)h[2] | ((int)h[3] << 16);
    pk[2] = (int)h[4] | ((int)h[5] << 16);
    pk[3] = (int)h[6] | ((int)h[7] << 16);
    *(i32x4*)&Ws[xn * 40 + kq * 8] = pk;
  };

  LOAD(ks0);
  for (int ks = ks0; ks < ks1; ++ks) {
    __syncthreads();           // prev compute done, LDS free
    STORE();
    __syncthreads();           // tile ready
    if (ks + 1 < ks1) LOAD(ks + 1);  // prefetch next into regs (hides under MFMA)

    bf16x8 af[8], bfr[4];
    #pragma unroll
    for (int mf = 0; mf < 8; ++mf)
      af[mf] = *(const bf16x8*)&Xs[(wr * 128 + mf * 16 + l15) * 40 + l4 * 8];
    #pragma unroll
    for (int nf = 0; nf < 4; ++nf)
      bfr[nf] = *(const bf16x8*)&Ws[(wc * 64 + nf * 16 + l15) * 40 + l4 * 8];
    #pragma unroll
    for (int mf = 0; mf < 8; ++mf)
      #pragma unroll
      for (int nf = 0; nf < 4; ++nf)
        acc[mf][nf] = __builtin_amdgcn_mfma_f32_16x16x32_bf16(af[mf], bfr[nf], acc[mf][nf], 0, 0, 0);
  }

  float* outp = part + (size_t)split * B_ * Npad;
  #pragma unroll
  for (int mf = 0; mf < 8; ++mf)
    #pragma unroll
    for (int nf = 0; nf < 4; ++nf) {
      int col = n0 + wc * 64 + nf * 16 + l15;
      int rb = wr * 128 + mf * 16 + l4 * 4;
      #pragma unroll
      for (int r = 0; r < 4; ++r)
        outp[(size_t)(rb + r) * Npad + col] = acc[mf][nf][r];
    }
}

// ---------------------------------------------------------------------------
// Reduce split-K partials + bias + ReLU -> bf16 K-tiled activations
// ---------------------------------------------------------------------------
__global__ void k_reduce(const float* __restrict__ part, const float* __restrict__ bias,
                         u16* __restrict__ Ht, int S, int Npad, int Nout, int Nvalid) {
  int idx = blockIdx.x * 256 + threadIdx.x;
  int perRow = Nout >> 2;
  if (idx >= B_ * perRow) return;
  int b = idx / perRow;
  int n = (idx - b * perRow) * 4;
  float v[4] = {0.f, 0.f, 0.f, 0.f};
  for (int s = 0; s < S; ++s) {
    const f32x4 p = *(const f32x4*)&part[(size_t)s * B_ * Npad + (size_t)b * Npad + n];
    #pragma unroll
    for (int r = 0; r < 4; ++r) v[r] += p[r];
  }
  u16x4 o;
  #pragma unroll
  for (int r = 0; r < 4; ++r) {
    float bi = (n + r < Nvalid) ? bias[n + r] : 0.f;
    o[r] = f2bf(fmaxf(v[r] + bi, 0.f));
  }
  *(u16x4*)&Ht[(size_t)(n >> 5) * 16384 + b * 32 + (n & 31)] = o;
}

// ---------------------------------------------------------------------------
// Tail: layers 3 (313->78) and 4 (78->2), fp32, one block per batch row
// ---------------------------------------------------------------------------
__global__ void k_tail(const u16* __restrict__ H3t,
                       const float* __restrict__ W3, const float* __restrict__ b3,
                       const float* __restrict__ W4, const float* __restrict__ b4,
                       float* __restrict__ out) {
  __shared__ float h3[320];
  __shared__ float h4[80];
  int b = blockIdx.x, tid = threadIdx.x;  // 128 threads
  for (int i = tid; i < 313; i += 128)
    h3[i] = bf2f(H3t[(size_t)(i >> 5) * 16384 + b * 32 + (i & 31)]);
  __syncthreads();
  if (tid < 78) {
    float a = b3[tid];
    for (int k = 0; k < 313; ++k) a += h3[k] * W3[k * 78 + tid];
    h4[tid] = fmaxf(a, 0.f);
  }
  __syncthreads();
  if (tid < 2) {
    float a = b4[tid];
    for (int k = 0; k < 78; ++k) a += h4[k] * W4[k * 2 + tid];
    out[b * 2 + tid] = a;
  }
}

// ---------------------------------------------------------------------------
extern "C" void kernel_launch(void* const* d_in, const int* in_sizes, int n_in,
                              void* d_out, int out_size, void* d_ws, size_t ws_size,
                              hipStream_t stream) {
  const float* expr = (const float*)d_in[0];
  const int*   cc   = (const int*)d_in[1];
  const float* cnc  = (const float*)d_in[2];
  const float* bw1  = (const float*)d_in[3];
  const float* bb1  = (const float*)d_in[4];
  const float* bw2  = (const float*)d_in[5];
  const float* bb2  = (const float*)d_in[6];
  const float* gw   = (const float*)d_in[7];
  const float* gb   = (const float*)d_in[8];
  const float* race = (const float*)d_in[9];
  const float* eth  = (const float*)d_in[10];
  const float* inter= (const float*)d_in[11];
  const float* prot = (const float*)d_in[12];
  const float* mw   = (const float*)d_in[13];
  const float* mb   = (const float*)d_in[14];
  const float* w0 = (const float*)d_in[15]; const float* b0 = (const float*)d_in[16];
  const float* w1 = (const float*)d_in[17]; const float* b1 = (const float*)d_in[18];
  const float* w2 = (const float*)d_in[19]; const float* b2 = (const float*)d_in[20];
  const float* w3 = (const float*)d_in[21]; const float* b3 = (const float*)d_in[22];
  const float* w4 = (const float*)d_in[23]; const float* b4 = (const float*)d_in[24];

  // workspace layout (bytes):
  //  Xt : 627*16384*2  = 20.55 MB   (X, K-tiled bf16, K=20064)
  //  H1t: 160*16384*2  =  5.24 MB   (K=5120)
  //  H2t:  40*16384*2  =  1.31 MB   (K=1280)
  //  H3t:  10*16384*2  =  0.33 MB   (K=320)
  //  part: 62.91 MB fp32 (max over layers)        total ~90.3 MB
  u16* Xt  = (u16*)d_ws;
  u16* H1t = Xt  + (size_t)627 * 16384;
  u16* H2t = H1t + (size_t)160 * 16384;
  u16* H3t = H2t + (size_t)40 * 16384;
  float* part = (float*)(H3t + (size_t)10 * 16384);

  // gene micro-MLP -> X cols [0,20000)
  k_gene<<<dim3(79, 16), 256, 0, stream>>>(expr, bw1, bb1, bw2, bb2, gw, gb, Xt);
  // clinical -> X cols [20000,20064) (incl. zero pad)
  k_clin<<<1, 512, 0, stream>>>(cc, cnc, race, eth, inter, prot, mw, mb, Xt);

  // L0: (512 x 20038) @ (20038 x 5009), split-K=6
  k_gemm<<<dim3(40, 6), 512, 0, stream>>>(Xt, w0, part, 627, 20038, 5009, 5120);
  k_reduce<<<2560, 256, 0, stream>>>(part, b0, H1t, 6, 5120, 5120, 5009);

  // L1: (512 x 5009) @ (5009 x 1252), split-K=24
  k_gemm<<<dim3(10, 24), 512, 0, stream>>>(H1t, w1, part, 160, 5009, 1252, 1280);
  k_reduce<<<640, 256, 0, stream>>>(part, b1, H2t, 24, 1280, 1280, 1252);

  // L2: (512 x 1252) @ (1252 x 313), split-K=40
  k_gemm<<<dim3(3, 40), 512, 0, stream>>>(H2t, w2, part, 40, 1252, 313, 384);
  k_reduce<<<160, 256, 0, stream>>>(part, b2, H3t, 40, 384, 320, 313);

  // L3+L4 tail, fp32
  k_tail<<<512, 128, 0, stream>>>(H3t, w3, b3, w4, b4, (float*)d_out);
}